// Round 2
// baseline (373.299 us; speedup 1.0000x reference)
//
#include <hip/hip_runtime.h>
#include <math.h>

#define TOKENS 8192
#define DDIM   4096
#define NE     16
#define NOUT   32
#define BKA    32
#define BMA    256
#define XSTR   260   // padded LDS row stride for x tile (floats)
#define WSTR   36    // padded LDS row stride for w tile (floats)

#define OUT_BAL  32768
#define OUT_LOAD 32769
#define OUT_IMP  32785
#define OUT_IDX  32801

// ---------------------------------------------------------------------------
// Kernel A: fused tall-skinny GEMM partials, K-split nkc ways.
// P[kcI][o][t] = dot(x[t, kc:kc+kchunk], W[o, kc:kc+kchunk]); o<16->Wg1 else Wn.
// Block: 256 threads, thread tile = 4 tokens x 8 outputs, tokens strided by 64
// so every P store / LDS compute read is lane-consecutive.
// ---------------------------------------------------------------------------
__global__ __launch_bounds__(256, 2) void gate_gemm_partial(
    const float* __restrict__ x,
    const float* __restrict__ Wg1,
    const float* __restrict__ Wn,
    float* __restrict__ P,        // [nkc][NOUT][TOKENS]
    int kchunk)
{
    __shared__ float xs[BKA * XSTR];   // x transposed: [k][token]
    __shared__ float wsh[BKA * WSTR];  // w transposed: [k][out]

    const int tid = threadIdx.x;
    const int t0  = blockIdx.x * BMA;
    const int kc  = blockIdx.y * kchunk;
    const int tg  = tid & 63;   // token lane: tokens {tg, tg+64, tg+128, tg+192}
    const int og  = tid >> 6;   // output group of 8 (wave-uniform!)

    float acc[4][8];
#pragma unroll
    for (int i = 0; i < 4; ++i)
#pragma unroll
        for (int j = 0; j < 8; ++j) acc[i][j] = 0.0f;

    const int ns = kchunk / BKA;
    for (int s = 0; s < ns; ++s) {
        const int kb = kc + s * BKA;
        // stage x: 256 tokens x 32 k. 8 consecutive threads cover one token's
        // 128B row segment; write transposed into LDS.
#pragma unroll
        for (int p = 0; p < 8; ++p) {
            const int i2 = p * 256 + tid;
            const int ti = i2 >> 3;
            const int kf = i2 & 7;
            const float4 v = *(const float4*)(x + (size_t)(t0 + ti) * DDIM + kb + kf * 4);
            xs[(kf * 4 + 0) * XSTR + ti] = v.x;
            xs[(kf * 4 + 1) * XSTR + ti] = v.y;
            xs[(kf * 4 + 2) * XSTR + ti] = v.z;
            xs[(kf * 4 + 3) * XSTR + ti] = v.w;
        }
        // stage w: 32 outputs x 32 k, one float4 per thread
        {
            const int o  = tid & 31;
            const int kf = tid >> 5;  // 0..7
            const float* wrow = (o < NE) ? (Wg1 + (size_t)o * DDIM)
                                         : (Wn  + (size_t)(o - NE) * DDIM);
            const float4 w = *(const float4*)(wrow + kb + kf * 4);
            wsh[(kf * 4 + 0) * WSTR + o] = w.x;
            wsh[(kf * 4 + 1) * WSTR + o] = w.y;
            wsh[(kf * 4 + 2) * WSTR + o] = w.z;
            wsh[(kf * 4 + 3) * WSTR + o] = w.w;
        }
        __syncthreads();
#pragma unroll
        for (int k = 0; k < BKA; ++k) {
            // x reads: lanes consecutive -> conflict-free b32
            const float xv0 = xs[k * XSTR + 0 * 64 + tg];
            const float xv1 = xs[k * XSTR + 1 * 64 + tg];
            const float xv2 = xs[k * XSTR + 2 * 64 + tg];
            const float xv3 = xs[k * XSTR + 3 * 64 + tg];
            // w reads: wave-uniform address -> LDS broadcast
            const float4 wa = *(const float4*)&wsh[k * WSTR + og * 8];
            const float4 wb = *(const float4*)&wsh[k * WSTR + og * 8 + 4];
            const float wv[8] = {wa.x, wa.y, wa.z, wa.w, wb.x, wb.y, wb.z, wb.w};
#pragma unroll
            for (int j = 0; j < 8; ++j) {
                acc[0][j] = fmaf(xv0, wv[j], acc[0][j]);
                acc[1][j] = fmaf(xv1, wv[j], acc[1][j]);
                acc[2][j] = fmaf(xv2, wv[j], acc[2][j]);
                acc[3][j] = fmaf(xv3, wv[j], acc[3][j]);
            }
        }
        __syncthreads();
    }

    // Plain stores (deterministic, no atomics, no memset of P needed).
    const size_t base = (size_t)blockIdx.y * NOUT * TOKENS;
#pragma unroll
    for (int j = 0; j < 8; ++j) {
        const int o = og * 8 + j;
#pragma unroll
        for (int i = 0; i < 4; ++i)
            P[base + (size_t)o * TOKENS + t0 + i * 64 + tg] = acc[i][j];
    }
}

// ---------------------------------------------------------------------------
// Kernel B: per-token epilogue. One thread per token, 64-thread blocks.
// ---------------------------------------------------------------------------
__global__ __launch_bounds__(64) void gate_epilogue(
    const float* __restrict__ P,
    const float* __restrict__ noise,
    const float* __restrict__ Wg2,
    float* __restrict__ out,
    float* __restrict__ gacc,   // [0..15] importance, [16..31] load
    int nkc)
{
    __shared__ float w2[NE * NE];
    __shared__ float s_imp[NE];
    __shared__ float s_load[NE];

    const int tid = threadIdx.x;
    ((float4*)w2)[tid] = ((const float4*)Wg2)[tid];   // 64 * 4 = 256 floats
    if (tid < NE) { s_imp[tid] = 0.0f; s_load[tid] = 0.0f; }
    __syncthreads();

    const int t = blockIdx.x * 64 + tid;

    // sum K-split partials (deterministic order)
    float g1[NE], nn[NE];
#pragma unroll
    for (int e = 0; e < NE; ++e) {
        float s = 0.0f;
        for (int c = 0; c < nkc; ++c)
            s += P[(size_t)c * NOUT * TOKENS + (size_t)e * TOKENS + t];
        g1[e] = s;
    }
#pragma unroll
    for (int e = 0; e < NE; ++e) {
        float s = 0.0f;
        for (int c = 0; c < nkc; ++c)
            s += P[(size_t)c * NOUT * TOKENS + (size_t)(NE + e) * TOKENS + t];
        nn[e] = s;
    }

    float h[NE];
#pragma unroll
    for (int e = 0; e < NE; ++e) h[e] = tanhf(g1[e]);

    float gate[NE];
#pragma unroll
    for (int e = 0; e < NE; ++e) {
        float sum = 0.0f;
#pragma unroll
        for (int j = 0; j < NE; ++j) sum = fmaf(h[j], w2[e * NE + j], sum);
        gate[e] = sum;
    }

    float nv[NE];
#pragma unroll
    for (int r = 0; r < 4; ++r) {
        const float4 nz = *(const float4*)(noise + (size_t)t * NE + r * 4);
        nv[r * 4 + 0] = nz.x; nv[r * 4 + 1] = nz.y;
        nv[r * 4 + 2] = nz.z; nv[r * 4 + 3] = nz.w;
    }

    float nc[NE], ln[NE], lg[NE];
#pragma unroll
    for (int e = 0; e < NE; ++e) {
        const float v = nn[e];
        const float sp = fmaxf(v, 0.0f) + log1pf(expf(-fabsf(v))); // stable softplus
        nc[e] = sp + 0.01f;
        ln[e] = nv[e] * nc[e];
        lg[e] = gate[e] + ln[e];
    }

    // top-5 by masked argmax (strict > == lax.top_k lowest-index tie-break)
    float tv[5]; int tix[5];
    unsigned mask = 0;
#pragma unroll
    for (int r = 0; r < 5; ++r) {
        float best = -INFINITY; int bi = 0;
#pragma unroll
        for (int e = 0; e < NE; ++e) {
            const bool ok = !((mask >> e) & 1u) && (lg[e] > best);
            best = ok ? lg[e] : best;
            bi   = ok ? e     : bi;
        }
        tv[r] = best; tix[r] = bi; mask |= 1u << bi;
    }

    // softmax over top-4
    const float m = tv[0];
    float ex[4]; float ssum = 0.0f;
#pragma unroll
    for (int r = 0; r < 4; ++r) { ex[r] = expf(tv[r] - m); ssum += ex[r]; }
    const float inv = 1.0f / ssum;

    float4 sc; sc.x = ex[0]*inv; sc.y = ex[1]*inv; sc.z = ex[2]*inv; sc.w = ex[3]*inv;
    *(float4*)(out + (size_t)t * 4) = sc;
    // indices region starts at float offset 32801 (not 16B aligned) -> scalar
    out[OUT_IDX + (size_t)t * 4 + 0] = (float)tix[0];
    out[OUT_IDX + (size_t)t * 4 + 1] = (float)tix[1];
    out[OUT_IDX + (size_t)t * 4 + 2] = (float)tix[2];
    out[OUT_IDX + (size_t)t * 4 + 3] = (float)tix[3];

    // importance
    atomicAdd(&s_imp[tix[0]], ex[0] * inv);
    atomicAdd(&s_imp[tix[1]], ex[1] * inv);
    atomicAdd(&s_imp[tix[2]], ex[2] * inv);
    atomicAdd(&s_imp[tix[3]], ex[3] * inv);

    // load: ndtr((gate - thr)/nc), thr selected by is_in = logits_noise > thr_in
    const float thr_in  = tv[4];
    const float thr_out = tv[3];
#pragma unroll
    for (int e = 0; e < NE; ++e) {
        const float thr = (ln[e] > thr_in) ? thr_in : thr_out;
        const float arg = (gate[e] - thr) / nc[e];
        const float pr  = 0.5f * erfcf(-arg * 0.70710678118654752440f); // ndtr
        atomicAdd(&s_load[e], pr);
    }
    __syncthreads();

    if (tid < NE)            atomicAdd(gacc + tid, s_imp[tid]);
    else if (tid < 2 * NE)   atomicAdd(gacc + tid, s_load[tid - NE]);
}

// ---------------------------------------------------------------------------
// Kernel C: balance loss + copy-out of load/importance.
// ---------------------------------------------------------------------------
__global__ void gate_finalize(const float* __restrict__ gacc, float* __restrict__ out)
{
    const int tid = threadIdx.x;
    if (tid == 0) {
        double mi = 0.0, ml = 0.0;
        for (int e = 0; e < NE; ++e) { mi += gacc[e]; ml += gacc[NE + e]; }
        mi /= NE; ml /= NE;
        double vi = 0.0, vl = 0.0;
        for (int e = 0; e < NE; ++e) {
            const double di = gacc[e] - mi;      vi += di * di;
            const double dl = gacc[NE + e] - ml; vl += dl * dl;
        }
        vi /= (NE - 1); vl /= (NE - 1);
        const double cvi = vi / (mi * mi + 1e-10);
        const double cvl = vl / (ml * ml + 1e-10);
        out[OUT_BAL] = (float)(0.01 * (cvi + cvl));
    }
    if (tid < NE) {
        out[OUT_LOAD + tid] = gacc[NE + tid];  // load
        out[OUT_IMP  + tid] = gacc[tid];       // importance
    }
}

extern "C" void kernel_launch(void* const* d_in, const int* in_sizes, int n_in,
                              void* d_out, int out_size, void* d_ws, size_t ws_size,
                              hipStream_t stream)
{
    const float* x     = (const float*)d_in[0];
    const float* noise = (const float*)d_in[1];
    const float* Wg1   = (const float*)d_in[2];
    const float* Wg2   = (const float*)d_in[3];
    const float* Wn    = (const float*)d_in[4];
    float* out = (float*)d_out;

    // ws layout: gacc[64 floats pad] | P[nkc][NOUT][TOKENS]
    float* gacc = (float*)d_ws;
    float* P    = gacc + 64;

    // pick largest power-of-two K-split that fits ws (never write past ws_size)
    int nkc = 16;
    while (nkc > 1 && 256 + (size_t)nkc * NOUT * TOKENS * sizeof(float) > ws_size)
        nkc >>= 1;
    const int kchunk = DDIM / nkc;

    hipMemsetAsync(gacc, 0, 32 * sizeof(float), stream);

    dim3 gA(TOKENS / BMA, nkc);
    gate_gemm_partial<<<gA, 256, 0, stream>>>(x, Wg1, Wn, P, kchunk);
    gate_epilogue<<<TOKENS / 64, 64, 0, stream>>>(P, noise, Wg2, out, gacc, nkc);
    gate_finalize<<<1, 64, 0, stream>>>(gacc, out);
}

// Round 3
// 237.681 us; speedup vs baseline: 1.5706x; 1.5706x over previous
//
#include <hip/hip_runtime.h>
#include <math.h>

#define TOKENS 8192
#define DDIM   4096
#define NE     16
#define NOUT   32
#define BKA    32
#define BMA    128
#define XSTR   134   // padded LDS row stride (floats), even -> 8B-aligned b64 reads

#define OUT_BAL  32768
#define OUT_LOAD 32769
#define OUT_IMP  32785
#define OUT_IDX  32801

// ---------------------------------------------------------------------------
// Kernel A: fused tall-skinny GEMM partials, K-split nkc ways.
// P[c][t][o] = dot(x[t, kc:kc+kchunk], W[o, :]);  o<16 -> Wg1 row o, else Wn.
// 256 threads: og = tid>>6 (8 outputs, wave-uniform via readfirstlane so W
// loads go through the SCALAR pipe / constant cache), tg = tid&63 -> tokens
// {2tg, 2tg+1} read from LDS as one b64. 512 blocks = 2/CU, 8 waves/CU.
// ---------------------------------------------------------------------------
__global__ __launch_bounds__(256, 2) void gate_gemm_partial(
    const float* __restrict__ x,
    const float* __restrict__ Wg1,
    const float* __restrict__ Wn,
    float* __restrict__ P,        // [nkc][TOKENS][NOUT]
    int kchunk)
{
    __shared__ float xs[BKA * XSTR];   // x transposed: [k][token]

    const int tid = threadIdx.x;
    const int t0  = blockIdx.x * BMA;
    const int kc  = blockIdx.y * kchunk;
    const int tg  = tid & 63;
    const int og  = __builtin_amdgcn_readfirstlane(tid >> 6);  // 0..3, uniform

    // wave-uniform weight row pointers -> scalar loads in the k-loop
    const float* wrow[8];
#pragma unroll
    for (int j = 0; j < 8; ++j) {
        const int o = og * 8 + j;
        wrow[j] = (o < NE) ? (Wg1 + (size_t)o * DDIM)
                           : (Wn  + (size_t)(o - NE) * DDIM);
    }

    float acc[2][8];
#pragma unroll
    for (int i = 0; i < 2; ++i)
#pragma unroll
        for (int j = 0; j < 8; ++j) acc[i][j] = 0.0f;

    const int ns = kchunk / BKA;
    for (int s = 0; s < ns; ++s) {
        const int kb = kc + s * BKA;
        // stage x: 128 tokens x 32 k. 8 consecutive lanes cover one token's
        // 128B row chunk (coalesced); write transposed into LDS.
#pragma unroll
        for (int p = 0; p < 4; ++p) {
            const int i2 = p * 256 + tid;
            const int ti = i2 >> 3;
            const int kf = i2 & 7;
            const float4 v = *(const float4*)(x + (size_t)(t0 + ti) * DDIM + kb + kf * 4);
            xs[(kf * 4 + 0) * XSTR + ti] = v.x;
            xs[(kf * 4 + 1) * XSTR + ti] = v.y;
            xs[(kf * 4 + 2) * XSTR + ti] = v.z;
            xs[(kf * 4 + 3) * XSTR + ti] = v.w;
        }
        __syncthreads();
#pragma unroll 4
        for (int k = 0; k < BKA; ++k) {
            const float2 xv = *(const float2*)&xs[k * XSTR + 2 * tg];
#pragma unroll
            for (int j = 0; j < 8; ++j) {
                const float w = wrow[j][kb + k];   // uniform -> s_load (L2-hot)
                acc[0][j] = fmaf(xv.x, w, acc[0][j]);
                acc[1][j] = fmaf(xv.y, w, acc[1][j]);
            }
        }
        __syncthreads();
    }

    // store P [c][t][o]: per-token float4 pairs (scatter on store side is cheap)
    const size_t cb = (size_t)blockIdx.y * TOKENS * NOUT;
#pragma unroll
    for (int i = 0; i < 2; ++i) {
        const int t = t0 + 2 * tg + i;
        float4 a; a.x = acc[i][0]; a.y = acc[i][1]; a.z = acc[i][2]; a.w = acc[i][3];
        float4 b; b.x = acc[i][4]; b.y = acc[i][5]; b.z = acc[i][6]; b.w = acc[i][7];
        *(float4*)(P + cb + (size_t)t * NOUT + og * 8)     = a;
        *(float4*)(P + cb + (size_t)t * NOUT + og * 8 + 4) = b;
    }
}

// ---------------------------------------------------------------------------
// Kernel B: epilogue, 16 lanes per token (lane = expert).
// 512 blocks x 256 threads; block covers 16 tokens; wave covers 4 tokens.
// ---------------------------------------------------------------------------
__global__ __launch_bounds__(256) void gate_epilogue(
    const float* __restrict__ P,
    const float* __restrict__ noise,
    const float* __restrict__ Wg2,
    float* __restrict__ out,
    float* __restrict__ gacc,   // [0..15] importance, [16..31] load
    int nkc)
{
    __shared__ float s_imp[NE];
    __shared__ float s_load[NE];

    const int tid = threadIdx.x;
    if (tid < NE) { s_imp[tid] = 0.0f; s_load[tid] = 0.0f; }
    __syncthreads();

    const int t     = blockIdx.x * 16 + (tid >> 4);
    const int e     = tid & 15;
    const int lane  = tid & 63;
    const int gbase = lane & 48;   // 16-lane group base within wave

    // sum K-split partials; P rows are [t][32] so lanes (e fast) coalesce
    float g1 = 0.0f, nn = 0.0f;
    for (int c = 0; c < nkc; ++c) {
        const float* pr = P + (size_t)c * TOKENS * NOUT + (size_t)t * NOUT;
        g1 += pr[e];
        nn += pr[NE + e];
    }

    // Wg2 row for this lane's expert
    float w2r[16];
#pragma unroll
    for (int r = 0; r < 4; ++r) {
        const float4 w = *(const float4*)(Wg2 + e * NE + r * 4);
        w2r[r * 4 + 0] = w.x; w2r[r * 4 + 1] = w.y;
        w2r[r * 4 + 2] = w.z; w2r[r * 4 + 3] = w.w;
    }

    const float h = tanhf(g1);
    float gate = 0.0f;
#pragma unroll
    for (int j = 0; j < 16; ++j) {
        const float hj = __shfl(h, gbase + j, 64);
        gate = fmaf(w2r[j], hj, gate);
    }

    const float nv  = noise[(size_t)t * NE + e];          // coalesced
    const float sp  = fmaxf(nn, 0.0f) + log1pf(expf(-fabsf(nn)));
    const float ncv = sp + 0.01f;
    const float ln  = nv * ncv;
    const float lg  = gate + ln;

    // top-5 across the 16-lane group: (val, idx) butterfly, lowest-idx tie-break
    float tv[5]; int tix[5];
    bool masked = false;
#pragma unroll
    for (int r = 0; r < 5; ++r) {
        float cv = masked ? -INFINITY : lg;
        int   ci = e;
#pragma unroll
        for (int st = 1; st < 16; st <<= 1) {
            const float ov = __shfl_xor(cv, st, 64);
            const int   oi = __shfl_xor(ci, st, 64);
            const bool take = (ov > cv) || (ov == cv && oi < ci);
            cv = take ? ov : cv;
            ci = take ? oi : ci;
        }
        tv[r] = cv; tix[r] = ci;
        masked = masked || (e == ci);
    }

    // softmax denominator over top-4 (all lanes, statically indexed)
    const float m = tv[0];
    const float ssum = expf(tv[0] - m) + expf(tv[1] - m)
                     + expf(tv[2] - m) + expf(tv[3] - m);
    const float inv = 1.0f / ssum;

    if (e < 4) {
        const float myv = (e == 0) ? tv[0] : (e == 1) ? tv[1] : (e == 2) ? tv[2] : tv[3];
        const int   myi = (e == 0) ? tix[0] : (e == 1) ? tix[1] : (e == 2) ? tix[2] : tix[3];
        const float sc  = expf(myv - m) * inv;
        out[(size_t)t * 4 + e]           = sc;
        out[OUT_IDX + (size_t)t * 4 + e] = (float)myi;
        atomicAdd(&s_imp[myi], sc);
    }

    // load: ndtr((gate-thr)/nc); is_in tests logits_noise > threshold_if_in
    const float thr = (ln > tv[4]) ? tv[4] : tv[3];
    const float pr  = 0.5f * erfcf((thr - gate) * 0.70710678118654752440f / ncv);
    atomicAdd(&s_load[e], pr);
    __syncthreads();

    if (tid < NE)          atomicAdd(gacc + tid, s_imp[tid]);
    else if (tid < 2 * NE) atomicAdd(gacc + tid, s_load[tid - NE]);
}

// ---------------------------------------------------------------------------
// Kernel C: balance loss + copy-out of load/importance.
// ---------------------------------------------------------------------------
__global__ void gate_finalize(const float* __restrict__ gacc, float* __restrict__ out)
{
    const int tid = threadIdx.x;
    if (tid == 0) {
        double mi = 0.0, ml = 0.0;
        for (int e = 0; e < NE; ++e) { mi += gacc[e]; ml += gacc[NE + e]; }
        mi /= NE; ml /= NE;
        double vi = 0.0, vl = 0.0;
        for (int e = 0; e < NE; ++e) {
            const double di = gacc[e] - mi;      vi += di * di;
            const double dl = gacc[NE + e] - ml; vl += dl * dl;
        }
        vi /= (NE - 1); vl /= (NE - 1);
        const double cvi = vi / (mi * mi + 1e-10);
        const double cvl = vl / (ml * ml + 1e-10);
        out[OUT_BAL] = (float)(0.01 * (cvi + cvl));
    }
    if (tid < NE) {
        out[OUT_LOAD + tid] = gacc[NE + tid];  // load
        out[OUT_IMP  + tid] = gacc[tid];       // importance
    }
}

extern "C" void kernel_launch(void* const* d_in, const int* in_sizes, int n_in,
                              void* d_out, int out_size, void* d_ws, size_t ws_size,
                              hipStream_t stream)
{
    const float* x     = (const float*)d_in[0];
    const float* noise = (const float*)d_in[1];
    const float* Wg1   = (const float*)d_in[2];
    const float* Wg2   = (const float*)d_in[3];
    const float* Wn    = (const float*)d_in[4];
    float* out = (float*)d_out;

    // ws layout: gacc[64 floats pad] | P[nkc][TOKENS][NOUT]
    float* gacc = (float*)d_ws;
    float* P    = gacc + 64;

    // largest power-of-two K-split that fits ws (never write past ws_size)
    int nkc = 16;
    while (nkc > 1 && 256 + (size_t)nkc * TOKENS * NOUT * sizeof(float) > ws_size)
        nkc >>= 1;
    const int kchunk = DDIM / nkc;

    hipMemsetAsync(gacc, 0, 32 * sizeof(float), stream);

    dim3 gA(TOKENS / BMA, nkc);                         // 64 x nkc blocks
    gate_gemm_partial<<<gA, 256, 0, stream>>>(x, Wg1, Wn, P, kchunk);
    gate_epilogue<<<TOKENS / 16, 256, 0, stream>>>(P, noise, Wg2, out, gacc, nkc);
    gate_finalize<<<1, 64, 0, stream>>>(gacc, out);
}